// Round 14
// baseline (439.134 us; speedup 1.0000x reference)
//
#include <hip/hip_runtime.h>
#include <hip/hip_bf16.h>
#include <stdint.h>

#define E_NUM 16
#define T_NUM 8192
#define H_DIM 1024
#define I_DIM 4096
#define MPE   512   // tokens per expert

typedef __attribute__((ext_vector_type(8))) short short8;
typedef __attribute__((ext_vector_type(4))) float f32x4;
using bf16 = __hip_bfloat16;

typedef const __attribute__((address_space(1))) void GLV;
typedef __attribute__((address_space(3))) void LDSV;

__device__ __forceinline__ uint32_t pack2_bf16(float a, float b) {
  union { float f; uint32_t u; } ua, ub;
  ua.f = a; ub.f = b;
  uint32_t x = ua.u + (0x7FFFu + ((ua.u >> 16) & 1u));
  uint32_t y = ub.u + (0x7FFFu + ((ub.u >> 16) & 1u));
  return (x >> 16) | (y & 0xFFFF0000u);
}

__device__ __forceinline__ short8 cvt8(f32x4 a, f32x4 b) {
  union { short8 s; __hip_bfloat162 h[4]; } r;
  r.h[0] = __float22bfloat162_rn({a[0], a[1]});
  r.h[1] = __float22bfloat162_rn({a[2], a[3]});
  r.h[2] = __float22bfloat162_rn({b[0], b[1]});
  r.h[3] = __float22bfloat162_rn({b[2], b[3]});
  return r.s;
}

// fast GELU (validated R10/R12/R13: absmax unchanged at 0.03125)
__device__ __forceinline__ float fast_gelu(float x) {
  const float p = x * fmaf(x * x, -0.0713548162726f, -1.59576912161f);
  return x * __builtin_amdgcn_rcpf(1.0f + __expf(p));
}

// ---------------- gather + cast: xp[r] = bf16(hs[perm[r]]) ----------------
__global__ __launch_bounds__(256)
void gather_cast_kernel(const float* __restrict__ hs, const int* __restrict__ perm,
                        uint32_t* __restrict__ xp) {
  const int r = blockIdx.x;
  const int t = threadIdx.x;
  const int src = perm[r];
  float4 v = ((const float4*)(hs + (size_t)src * H_DIM))[t];
  uint2 o;
  o.x = pack2_bf16(v.x, v.y);
  o.y = pack2_bf16(v.z, v.w);
  ((uint2*)(xp + (size_t)r * (H_DIM / 2)))[t] = o;
}

// ---- GEMM1 (R13-validated, 189 us) + per-XCD parity-interleaved w2 cast ----
// grid 2048 x 512 thr.  XCD = orig&7 (round-robin dispatch), s = orig>>3.
// s odd  -> cast block: grid-stride fp32->bf16 over w2 (1024 blocks, even per XCD)
// s even -> gemm block: gid = xcd*128 + s/2 (m204-chunked), R13 g1 verbatim.
// h[e] = gelu(xp[e]*w1[e]^T + b1).  BM=256/BN=128/BK=32, 8 waves (4M x 2N).
template<int LOG_NBN>
__global__ __launch_bounds__(512, 2)
void moe_g1_cast_kernel(const bf16* __restrict__ A, const float* __restrict__ Bw,
                        const float* __restrict__ bias, bf16* __restrict__ Hout,
                        const float* __restrict__ csrc, uint32_t* __restrict__ cdst,
                        long n4) {
  constexpr int N = I_DIM, K = H_DIM;
  constexpr int NK = K / 32;
  __shared__ bf16  As[2][128 * 64];   // 16 KB each (pair-packed 256 rows)
  __shared__ float Bs[2][128 * 32];   // 16 KB each

  const int orig = blockIdx.x;
  const int xcd = orig & 7;
  const int s = orig >> 3;            // 0..255 per XCD
  const int tid = threadIdx.x;

  if (s & 1) {                        // ---- cast role (w2 fp32 -> bf16)
    const long cid = xcd * 128 + (s >> 1);      // 0..1023
    long i = cid * 512 + tid;
    const long step = 1024 * 512;
    for (; i < n4; i += step) {
      float4 v = ((const float4*)csrc)[i];
      uint2 o;
      o.x = pack2_bf16(v.x, v.y);
      o.y = pack2_bf16(v.z, v.w);
      ((uint2*)cdst)[i] = o;
    }
    return;
  }

  const int gid = xcd * 128 + (s >> 1);         // 0..1023, chunked per XCD
  const int bm = gid & 1;
  const int bn = (gid >> 1) & ((1 << LOG_NBN) - 1);
  const int e  = gid >> (1 + LOG_NBN);

  const int l = tid & 63;
  const int wv = tid >> 6;                 // 0..7
  const int wr = wv >> 1, wc = wv & 1;     // 4 M-waves x 2 N-waves
  const int fr = l & 15, fq = l >> 4;
  const int rx = fr & 7;

  const bf16*  Ae = A  + ((size_t)e * MPE + (size_t)bm * 256) * K;
  const float* Be = Bw + ((size_t)e * N + (size_t)bn * 128) * K;

  const int p0 = tid >> 3;
  const int ga = (tid & 7) ^ (p0 & 7);
  const bf16* As0 = Ae + (size_t)(p0      + 128 * (ga >> 2)) * K + (ga & 3) * 8;
  const bf16* As1 = Ae + (size_t)(p0 + 64 + 128 * (ga >> 2)) * K + (ga & 3) * 8;
  const float* Bs0 = Be + (size_t)p0 * K + ga * 4;
  const float* Bs1 = Be + (size_t)(p0 + 64) * K + ga * 4;

#define STAGE1(buf, kt)                                                            \
  {                                                                                \
    __builtin_amdgcn_global_load_lds((GLV*)(As0 + (kt) * 32),                      \
        (LDSV*)((char*)&As[buf][0] + tid * 16), 16, 0, 0);                         \
    __builtin_amdgcn_global_load_lds((GLV*)(As1 + (kt) * 32),                      \
        (LDSV*)((char*)&As[buf][0] + 8192 + tid * 16), 16, 0, 0);                  \
    __builtin_amdgcn_global_load_lds((GLV*)(Bs0 + (kt) * 32),                      \
        (LDSV*)((char*)&Bs[buf][0] + tid * 16), 16, 0, 0);                         \
    __builtin_amdgcn_global_load_lds((GLV*)(Bs1 + (kt) * 32),                      \
        (LDSV*)((char*)&Bs[buf][0] + 8192 + tid * 16), 16, 0, 0);                  \
  }

  const int aoff  = ((wr & 1) * 64 + fr) * 128 + ((((wr >> 1) << 2) | fq) ^ rx) * 16;
  const int b0off = (wc * 64 + fr) * 128 + (((fq << 1)) ^ rx) * 16;
  const int b1off = (wc * 64 + fr) * 128 + (((fq << 1) | 1) ^ rx) * 16;

  f32x4 acc[4][4];
#pragma unroll
  for (int m = 0; m < 4; ++m)
#pragma unroll
    for (int n = 0; n < 4; ++n) acc[m][n] = (f32x4){0.f, 0.f, 0.f, 0.f};

  STAGE1(0, 0);
  __syncthreads();

  for (int t = 0; t < NK; ++t) {
    const int cur = t & 1;
    if (t + 1 < NK) STAGE1(cur ^ 1, t + 1);

    short8 a8[4];
#pragma unroll
    for (int m = 0; m < 4; ++m)
      a8[m] = *(const short8*)((const char*)&As[cur][0] + aoff + m * 2048);
    short8 b8[4];
#pragma unroll
    for (int n = 0; n < 4; ++n) {
      const f32x4 x0 = *(const f32x4*)((const char*)&Bs[cur][0] + b0off + n * 2048);
      const f32x4 x1 = *(const f32x4*)((const char*)&Bs[cur][0] + b1off + n * 2048);
      b8[n] = cvt8(x0, x1);
    }
#pragma unroll
    for (int m = 0; m < 4; ++m)
#pragma unroll
      for (int n = 0; n < 4; ++n)
        acc[m][n] = __builtin_amdgcn_mfma_f32_16x16x32_bf16(a8[m], b8[n], acc[m][n], 0, 0, 0);

    __syncthreads();
  }
#undef STAGE1

  float bv[4];
#pragma unroll
  for (int n = 0; n < 4; ++n)
    bv[n] = bias[(size_t)e * N + bn * 128 + wc * 64 + n * 16 + fr];

  bf16* He = Hout + (size_t)e * MPE * N;
#pragma unroll
  for (int m = 0; m < 4; ++m) {
#pragma unroll
    for (int j = 0; j < 4; ++j) {
      const int row = bm * 256 + wr * 64 + m * 16 + fq * 4 + j;
#pragma unroll
      for (int n = 0; n < 4; ++n) {
        const int col = bn * 128 + wc * 64 + n * 16 + fr;
        He[(size_t)row * N + col] = __float2bfloat16(fast_gelu(acc[m][n][j] + bv[n]));
      }
    }
  }
}

// ------- GEMM2: pure-bf16 (R9-validated structure, 0 conflicts) -------------
// out[perm[grow]] = h[e]*w2b[e]^T + b2.  128x128 tile, BK=64, 256 thr, 2 blk/CU.
template<int N, int K, int LOG_NBN, int NWG>
__global__ __launch_bounds__(256, 2)
void moe_g2_b16_kernel(const bf16* __restrict__ A, const bf16* __restrict__ Bw,
                       const float* __restrict__ bias, float* __restrict__ Oout,
                       const int* __restrict__ perm) {
  constexpr int NK = K / 64;
  __shared__ bf16 As[2][128 * 64];
  __shared__ bf16 Bs[2][128 * 64];

  constexpr int qx = NWG >> 3;
  const int orig = blockIdx.x;
  const int wg = (orig & 7) * qx + (orig >> 3);
  const int bm = wg & 3;
  const int bn = (wg >> 2) & ((1 << LOG_NBN) - 1);
  const int e  = wg >> (2 + LOG_NBN);

  const int tid = threadIdx.x;
  const int l = tid & 63;
  const int wv = tid >> 6;
  const int wr = wv >> 1, wc = wv & 1;
  const int fr = l & 15, fq = l >> 4;
  const int rx = fr & 7;

  const bf16* Ae = A  + ((size_t)e * MPE + (size_t)bm * 128) * K;
  const bf16* Be = Bw + ((size_t)e * N + (size_t)bn * 128) * K;

  const int sr = tid >> 3;
  const int swz = ((tid & 7) ^ (sr & 7)) << 3;
  const bf16* Asrc = Ae + (size_t)sr * K + swz;
  const bf16* Bsrc = Be + (size_t)sr * K + swz;

#define STAGE_B16(buf, kt)                                                          \
  {                                                                                 \
    _Pragma("unroll")                                                               \
    for (int i = 0; i < 4; ++i)                                                     \
      __builtin_amdgcn_global_load_lds((GLV*)(Asrc + (size_t)i * 32 * K + (kt) * 64), \
                                       (LDSV*)&As[buf][(i * 256 + wv * 64) * 8], 16, 0, 0); \
    _Pragma("unroll")                                                               \
    for (int i = 0; i < 4; ++i)                                                     \
      __builtin_amdgcn_global_load_lds((GLV*)(Bsrc + (size_t)i * 32 * K + (kt) * 64), \
                                       (LDSV*)&Bs[buf][(i * 256 + wv * 64) * 8], 16, 0, 0); \
  }

  f32x4 acc[4][4];
#pragma unroll
  for (int m = 0; m < 4; ++m)
#pragma unroll
    for (int n = 0; n < 4; ++n) acc[m][n] = (f32x4){0.f, 0.f, 0.f, 0.f};

  STAGE_B16(0, 0);
  __syncthreads();

  for (int t = 0; t < NK; ++t) {
    const int cur = t & 1, nxt = cur ^ 1;
    if (t + 1 < NK) STAGE_B16(nxt, t + 1);

#pragma unroll
    for (int kk = 0; kk < 2; ++kk) {
      const int ch = ((kk * 4 + fq) ^ rx) << 3;
      short8 a8[4], b8[4];
#pragma unroll
      for (int m = 0; m < 4; ++m)
        a8[m] = *(const short8*)&As[cur][(wr * 64 + m * 16 + fr) * 64 + ch];
#pragma unroll
      for (int n = 0; n < 4; ++n)
        b8[n] = *(const short8*)&Bs[cur][(wc * 64 + n * 16 + fr) * 64 + ch];
#pragma unroll
      for (int m = 0; m < 4; ++m)
#pragma unroll
        for (int n = 0; n < 4; ++n)
          acc[m][n] = __builtin_amdgcn_mfma_f32_16x16x32_bf16(a8[m], b8[n], acc[m][n], 0, 0, 0);
    }
    __syncthreads();
  }
#undef STAGE_B16

  float bv[4];
#pragma unroll
  for (int n = 0; n < 4; ++n)
    bv[n] = bias[(size_t)e * N + bn * 128 + wc * 64 + n * 16 + fr];

#pragma unroll
  for (int m = 0; m < 4; ++m) {
#pragma unroll
    for (int j = 0; j < 4; ++j) {
      const int grow = e * MPE + bm * 128 + wr * 64 + m * 16 + fq * 4 + j;
      const int drow = perm[grow];
      float* orow = Oout + (size_t)drow * N;
#pragma unroll
      for (int n = 0; n < 4; ++n) {
        const int col = bn * 128 + wc * 64 + n * 16 + fr;
        orow[col] = acc[m][n][j] + bv[n];
      }
    }
  }
}

// ------- fp32-B split-K GEMM2 + partial-reduce LN (fallback tier only) ------
template<int KSPLIT, int N, int KFULL, int KLEN, int LOG_NBN>
__global__ __launch_bounds__(1024, 4)
void moe_g2_f32_kernel(const bf16* __restrict__ A, const float* __restrict__ Bw,
                       float* __restrict__ Pout) {
  constexpr int NK = KLEN / 32;
  __shared__ bf16  As[2][512 * 32];
  __shared__ float Bs[2][128 * 32];

  const int nwg = gridDim.x, qx = nwg >> 3, orig = blockIdx.x;
  const int wg = (orig & 7) * qx + (orig >> 3);
  const int bn   = wg & ((1 << LOG_NBN) - 1);
  const int rest = wg >> LOG_NBN;
  const int ks = (KSPLIT == 2) ? (rest & 1) : 0;
  const int e  = (KSPLIT == 2) ? (rest >> 1) : rest;
  const int K0 = ks * KLEN;

  const int tid = threadIdx.x;
  const int l = tid & 63;
  const int w = tid >> 6;
  const int wr = w >> 1, wc = w & 1;
  const int fr = l & 15, fq = l >> 4;
  const int rx = fr & 7;

  const bf16*  Ae = A  + (size_t)e * MPE * KFULL + K0;
  const float* Be = Bw + ((size_t)e * N + (size_t)bn * 128) * KFULL + K0;

  const int apq = tid >> 3;
  const int ag  = (tid & 7) ^ (apq & 7);
  const bf16* As0 = Ae + (size_t)(apq       + 256 * (ag >> 2)) * KFULL + (ag & 3) * 8;
  const bf16* As1 = Ae + (size_t)(apq + 128 + 256 * (ag >> 2)) * KFULL + (ag & 3) * 8;
  const float* Bsrc = Be + (size_t)(tid >> 3) * KFULL + ((tid & 7) ^ ((tid >> 3) & 7)) * 4;

  const int aso = (((((wr >> 2) << 2)) | fq) ^ rx) * 8;
  const int bp0 = (((fq << 1))     ^ rx) * 4;
  const int bp1 = (((fq << 1) | 1) ^ rx) * 4;

#define STAGE2(buf, kt)                                                             \
  {                                                                                 \
    __builtin_amdgcn_global_load_lds((GLV*)(As0 + (kt) * 32),                       \
                                     (LDSV*)&As[buf][tid * 8], 16, 0, 0);           \
    __builtin_amdgcn_global_load_lds((GLV*)(As1 + (kt) * 32),                       \
                                     (LDSV*)&As[buf][(1024 + tid) * 8], 16, 0, 0);  \
    __builtin_amdgcn_global_load_lds((GLV*)(Bsrc + (kt) * 32),                      \
                                     (LDSV*)&Bs[buf][tid * 4], 16, 0, 0);           \
  }

  f32x4 acc[4][4];
#pragma unroll
  for (int m = 0; m < 4; ++m)
#pragma unroll
    for (int n = 0; n < 4; ++n) acc[m][n] = (f32x4){0.f, 0.f, 0.f, 0.f};

  STAGE2(0, 0);
  __syncthreads();

  for (int t = 0; t < NK; ++t) {
    const int cur = t & 1;
    if (t + 1 < NK) STAGE2(cur ^ 1, t + 1);

    short8 a8[4];
#pragma unroll
    for (int m = 0; m < 4; ++m)
      a8[m] = *(const short8*)&As[cur][((wr & 3) * 64 + m * 16 + fr) * 64 + aso];
#pragma unroll
    for (int n = 0; n < 4; ++n) {
      const int col = wc * 64 + n * 16 + fr;
      const f32x4 x0 = *(const f32x4*)&Bs[cur][col * 32 + bp0];
      const f32x4 x1 = *(const f32x4*)&Bs[cur][col * 32 + bp1];
      const short8 b8 = cvt8(x0, x1);
#pragma unroll
      for (int m = 0; m < 4; ++m)
        acc[m][n] = __builtin_amdgcn_mfma_f32_16x16x32_bf16(a8[m], b8, acc[m][n], 0, 0, 0);
    }
    __syncthreads();
  }
#undef STAGE2

  float* Pd = Pout + (size_t)ks * T_NUM * H_DIM + (size_t)e * MPE * N;
#pragma unroll
  for (int m = 0; m < 4; ++m) {
#pragma unroll
    for (int j = 0; j < 4; ++j) {
      const int row = wr * 64 + m * 16 + fq * 4 + j;
#pragma unroll
      for (int n = 0; n < 4; ++n) {
        const int col = bn * 128 + wc * 64 + n * 16 + fr;
        Pd[(size_t)row * N + col] = acc[m][n][j];
      }
    }
  }
}

// ---------------- residual + LayerNorm (in place on out) ----------------
__global__ __launch_bounds__(256)
void ln_resid_kernel(float* __restrict__ out, const float* __restrict__ hs,
                     const float* __restrict__ gamma, const float* __restrict__ beta) {
  const int r = blockIdx.x;
  const int t = threadIdx.x;
  float4 o = ((const float4*)(out + (size_t)r * H_DIM))[t];
  float4 h = ((const float4*)(hs  + (size_t)r * H_DIM))[t];
  float v0 = o.x + h.x, v1 = o.y + h.y, v2 = o.z + h.z, v3 = o.w + h.w;
  float s  = v0 + v1 + v2 + v3;
  float sq = v0 * v0 + v1 * v1 + v2 * v2 + v3 * v3;
#pragma unroll
  for (int off = 32; off > 0; off >>= 1) {
    s  += __shfl_down(s, off);
    sq += __shfl_down(sq, off);
  }
  __shared__ float ss[4], ssq[4];
  const int wv = t >> 6;
  if ((t & 63) == 0) { ss[wv] = s; ssq[wv] = sq; }
  __syncthreads();
  s  = ss[0] + ss[1] + ss[2] + ss[3];
  sq = ssq[0] + ssq[1] + ssq[2] + ssq[3];
  const float mu  = s * (1.0f / (float)H_DIM);
  const float var = sq * (1.0f / (float)H_DIM) - mu * mu;
  const float rs  = rsqrtf(var + 1e-12f);
  float4 g = ((const float4*)gamma)[t];
  float4 b = ((const float4*)beta)[t];
  float4 rr;
  rr.x = (v0 - mu) * rs * g.x + b.x;
  rr.y = (v1 - mu) * rs * g.y + b.y;
  rr.z = (v2 - mu) * rs * g.z + b.z;
  rr.w = (v3 - mu) * rs * g.w + b.w;
  ((float4*)(out + (size_t)r * H_DIM))[t] = rr;
}

// -------- fallback: reduce partials + bias + residual + LN + scatter --------
__global__ __launch_bounds__(256)
void ln_resid2_kernel(float* __restrict__ out, const float* __restrict__ hs,
                      const float* __restrict__ p0, const float* __restrict__ p1,
                      const float* __restrict__ b2, const float* __restrict__ gamma,
                      const float* __restrict__ beta, const int* __restrict__ perm,
                      const int two) {
  const int r = blockIdx.x;
  const int t = threadIdx.x;
  const int e = r >> 9;
  const int drow = perm[r];
  float4 a = ((const float4*)(p0 + (size_t)r * H_DIM))[t];
  if (two) {
    float4 b = ((const float4*)(p1 + (size_t)r * H_DIM))[t];
    a.x += b.x; a.y += b.y; a.z += b.z; a.w += b.w;
  }
  float4 bb = ((const float4*)(b2 + (size_t)e * H_DIM))[t];
  float4 h  = ((const float4*)(hs + (size_t)drow * H_DIM))[t];
  float v0 = a.x + bb.x + h.x, v1 = a.y + bb.y + h.y;
  float v2 = a.z + bb.z + h.z, v3 = a.w + bb.w + h.w;
  float s  = v0 + v1 + v2 + v3;
  float sq = v0 * v0 + v1 * v1 + v2 * v2 + v3 * v3;
#pragma unroll
  for (int off = 32; off > 0; off >>= 1) {
    s  += __shfl_down(s, off);
    sq += __shfl_down(sq, off);
  }
  __shared__ float ss[4], ssq[4];
  const int wv = t >> 6;
  if ((t & 63) == 0) { ss[wv] = s; ssq[wv] = sq; }
  __syncthreads();
  s  = ss[0] + ss[1] + ss[2] + ss[3];
  sq = ssq[0] + ssq[1] + ssq[2] + ssq[3];
  const float mu  = s * (1.0f / (float)H_DIM);
  const float var = sq * (1.0f / (float)H_DIM) - mu * mu;
  const float rs  = rsqrtf(var + 1e-12f);
  float4 g = ((const float4*)gamma)[t];
  float4 b = ((const float4*)beta)[t];
  float4 rr;
  rr.x = (v0 - mu) * rs * g.x + b.x;
  rr.y = (v1 - mu) * rs * g.y + b.y;
  rr.z = (v2 - mu) * rs * g.z + b.z;
  rr.w = (v3 - mu) * rs * g.w + b.w;
  ((float4*)(out + (size_t)drow * H_DIM))[t] = rr;
}

extern "C" void kernel_launch(void* const* d_in, const int* in_sizes, int n_in,
                              void* d_out, int out_size, void* d_ws, size_t ws_size,
                              hipStream_t stream) {
  const float* hs    = (const float*)d_in[0];
  const int*   perm  = (const int*)d_in[1];
  const float* w1    = (const float*)d_in[2];
  const float* b1    = (const float*)d_in[3];
  const float* w2    = (const float*)d_in[4];
  const float* b2    = (const float*)d_in[5];
  const float* gamma = (const float*)d_in[6];
  const float* beta  = (const float*)d_in[7];
  float* out = (float*)d_out;

  const size_t MB = 1024ull * 1024ull;
  const long n4w2 = (long)E_NUM * H_DIM * I_DIM / 4;   // 16M float4

  bf16* xp   = (bf16*)d_ws;                       // [0, 16 MB)
  bf16* hbuf = (bf16*)((char*)d_ws + 16 * MB);    // [16, 80 MB)

  gather_cast_kernel<<<T_NUM, 256, 0, stream>>>(hs, perm, (uint32_t*)xp);

  if (ws_size >= 208 * MB) {
    // G1 (R13 gemm, 1024 blocks) + 1024 parity-interleaved w2-cast blocks
    bf16* w2b = (bf16*)((char*)d_ws + 80 * MB);   // [80, 208 MB)
    moe_g1_cast_kernel<5><<<2048, 512, 0, stream>>>(
        xp, w1, b1, hbuf, w2, (uint32_t*)w2b, n4w2);
    // G2: pure-bf16 (R9-validated), grid 4 bm x 8 bn x 16 e = 512
    moe_g2_b16_kernel<H_DIM, I_DIM, 3, 512><<<512, 256, 0, stream>>>(
        hbuf, w2b, b2, out, perm);
    ln_resid_kernel<<<T_NUM, 256, 0, stream>>>(out, hs, gamma, beta);
  } else {
    // fallback: R13 path (pure G1 + fp32 split-K G2 + fused reduce-LN)
    const size_t xp_b   = (size_t)T_NUM * H_DIM * sizeof(bf16);
    const size_t hbuf_b = (size_t)T_NUM * I_DIM * sizeof(bf16);
    const size_t part_b = (size_t)T_NUM * H_DIM * sizeof(float);
    float* pbuf = (float*)((char*)d_ws + xp_b + hbuf_b);
    moe_g1_cast_kernel<5><<<2048, 512, 0, stream>>>(
        xp, w1, b1, hbuf, nullptr, nullptr, 0);
    if (ws_size >= xp_b + hbuf_b + 2 * part_b) {
      moe_g2_f32_kernel<2, H_DIM, I_DIM, I_DIM / 2, 3>
          <<<256, 1024, 0, stream>>>(hbuf, w2, pbuf);
      ln_resid2_kernel<<<T_NUM, 256, 0, stream>>>(out, hs, pbuf,
                                                  pbuf + (size_t)T_NUM * H_DIM,
                                                  b2, gamma, beta, perm, 1);
    } else {
      moe_g2_f32_kernel<1, H_DIM, I_DIM, I_DIM, 3>
          <<<128, 1024, 0, stream>>>(hbuf, w2, pbuf);
      ln_resid2_kernel<<<T_NUM, 256, 0, stream>>>(out, hs, pbuf, nullptr,
                                                  b2, gamma, beta, perm, 0);
    }
  }
}

// Round 15
// 323.688 us; speedup vs baseline: 1.3567x; 1.3567x over previous
//
#include <hip/hip_runtime.h>
#include <hip/hip_bf16.h>
#include <stdint.h>

#define E_NUM 16
#define T_NUM 8192
#define H_DIM 1024
#define I_DIM 4096
#define MPE   512   // tokens per expert

typedef __attribute__((ext_vector_type(8))) short short8;
typedef __attribute__((ext_vector_type(4))) float f32x4;
using bf16 = __hip_bfloat16;

typedef const __attribute__((address_space(1))) void GLV;
typedef __attribute__((address_space(3))) void LDSV;

__device__ __forceinline__ uint32_t pack2_bf16(float a, float b) {
  union { float f; uint32_t u; } ua, ub;
  ua.f = a; ub.f = b;
  uint32_t x = ua.u + (0x7FFFu + ((ua.u >> 16) & 1u));
  uint32_t y = ub.u + (0x7FFFu + ((ub.u >> 16) & 1u));
  return (x >> 16) | (y & 0xFFFF0000u);
}

// 8 f32 (two f32x4) -> short8 of bf16 (RNE, v_cvt_pk_bf16_f32)
__device__ __forceinline__ short8 cvt8(f32x4 a, f32x4 b) {
  union { short8 s; __hip_bfloat162 h[4]; } r;
  r.h[0] = __float22bfloat162_rn({a[0], a[1]});
  r.h[1] = __float22bfloat162_rn({a[2], a[3]});
  r.h[2] = __float22bfloat162_rn({b[0], b[1]});
  r.h[3] = __float22bfloat162_rn({b[2], b[3]});
  return r.s;
}

// fast GELU (validated R10/R12/R13: absmax unchanged at 0.03125)
__device__ __forceinline__ float fast_gelu(float x) {
  const float p = x * fmaf(x * x, -0.0713548162726f, -1.59576912161f);
  return x * __builtin_amdgcn_rcpf(1.0f + __expf(p));
}

// ---------------- gather + cast: xp[r] = bf16(hs[perm[r]]) ----------------
__global__ __launch_bounds__(256)
void gather_cast_kernel(const float* __restrict__ hs, const int* __restrict__ perm,
                        uint32_t* __restrict__ xp) {
  const int r = blockIdx.x;
  const int t = threadIdx.x;
  const int src = perm[r];
  float4 v = ((const float4*)(hs + (size_t)src * H_DIM))[t];
  uint2 o;
  o.x = pack2_bf16(v.x, v.y);
  o.y = pack2_bf16(v.z, v.w);
  ((uint2*)(xp + (size_t)r * (H_DIM / 2)))[t] = o;
}

// ---------------- grouped GEMM, BM=512 (R8-validated structure) -------------
// C = A(bf16,[E][512][KFULL]) * B(f32,[E][N][KFULL])^T over K window.
// BM=512, BN=128, BK=32, 1024 thr = 16 waves (8M x 2N), acc 4x4 f32x4.
// LDS dbuf 96 KB.  EPI=1: gelu -> bf16 Hout via LDS-coalesced epilogue
// (fast_gelu + XOR-swizzled LDS transpose + 16B stores; the only change vs R8).
// EPI=0: f32 partial to Pout (split-K), R8 verbatim.
template<int EPI, int KSPLIT, int N, int KFULL, int KLEN, int LOG_NBN>
__global__ __launch_bounds__(1024, 4)
void moe_gemm_kernel(const bf16* __restrict__ A, const float* __restrict__ Bw,
                     const float* __restrict__ bias, bf16* __restrict__ Hout,
                     float* __restrict__ Pout) {
  constexpr int NK = KLEN / 32;
  __shared__ bf16  As[2][512 * 32];   // 32 KB each (also epilogue transpose buf)
  __shared__ float Bs[2][128 * 32];   // 16 KB each

  // bijective chunked XCD swizzle (m204); nwg % 8 == 0
  const int nwg = gridDim.x, qx = nwg >> 3, orig = blockIdx.x;
  const int wg = (orig & 7) * qx + (orig >> 3);
  const int bn   = wg & ((1 << LOG_NBN) - 1);
  const int rest = wg >> LOG_NBN;
  const int ks = (KSPLIT == 2) ? (rest & 1) : 0;
  const int e  = (KSPLIT == 2) ? (rest >> 1) : rest;
  const int K0 = ks * KLEN;

  const int tid = threadIdx.x;
  const int l = tid & 63;
  const int w = tid >> 6;                  // 0..15
  const int wr = w >> 1, wc = w & 1;       // 8 M-waves x 2 N-waves
  const int fr = l & 15, fq = l >> 4;
  const int rx = fr & 7;

  const bf16*  Ae = A  + (size_t)e * MPE * KFULL + K0;
  const float* Be = Bw + ((size_t)e * N + (size_t)bn * 128) * KFULL + K0;

  // A staging (R8-validated): lds-row p = i*128 + (tid>>3), slot s = tid&7,
  // g = s^(p&7); real row = p + 256*(g>>2), k-chunk (g&3)*8.
  const int apq = tid >> 3;
  const int ag  = (tid & 7) ^ (apq & 7);
  const bf16* As0 = Ae + (size_t)(apq       + 256 * (ag >> 2)) * KFULL + (ag & 3) * 8;
  const bf16* As1 = Ae + (size_t)(apq + 128 + 256 * (ag >> 2)) * KFULL + (ag & 3) * 8;

  // B staging (R8-validated): row = tid>>3, slot = tid&7, g = slot^(row&7)
  const float* Bsrc = Be + (size_t)(tid >> 3) * KFULL + ((tid & 7) ^ ((tid >> 3) & 7)) * 4;

  // fragment read offsets (R8-validated)
  const int aso = (((((wr >> 2) << 2)) | fq) ^ rx) * 8;
  const int bp0 = (((fq << 1))     ^ rx) * 4;
  const int bp1 = (((fq << 1) | 1) ^ rx) * 4;

#define STAGE(buf, kt)                                                              \
  {                                                                                 \
    __builtin_amdgcn_global_load_lds((GLV*)(As0 + (kt) * 32),                       \
                                     (LDSV*)&As[buf][tid * 8], 16, 0, 0);           \
    __builtin_amdgcn_global_load_lds((GLV*)(As1 + (kt) * 32),                       \
                                     (LDSV*)&As[buf][(1024 + tid) * 8], 16, 0, 0);  \
    __builtin_amdgcn_global_load_lds((GLV*)(Bsrc + (kt) * 32),                      \
                                     (LDSV*)&Bs[buf][tid * 4], 16, 0, 0);           \
  }

  f32x4 acc[4][4];
#pragma unroll
  for (int m = 0; m < 4; ++m)
#pragma unroll
    for (int n = 0; n < 4; ++n) acc[m][n] = (f32x4){0.f, 0.f, 0.f, 0.f};

  // ---- prologue
  STAGE(0, 0);
  __syncthreads();

  for (int t = 0; t < NK; ++t) {
    const int cur = t & 1, nxt = cur ^ 1;
    if (t + 1 < NK) STAGE(nxt, t + 1);

    short8 a8[4];
#pragma unroll
    for (int m = 0; m < 4; ++m)
      a8[m] = *(const short8*)&As[cur][((wr & 3) * 64 + m * 16 + fr) * 64 + aso];

#pragma unroll
    for (int n = 0; n < 4; ++n) {
      const int col = wc * 64 + n * 16 + fr;
      const f32x4 x0 = *(const f32x4*)&Bs[cur][col * 32 + bp0];
      const f32x4 x1 = *(const f32x4*)&Bs[cur][col * 32 + bp1];
      const short8 b8 = cvt8(x0, x1);
#pragma unroll
      for (int m = 0; m < 4; ++m)
        acc[m][n] = __builtin_amdgcn_mfma_f32_16x16x32_bf16(a8[m], b8, acc[m][n], 0, 0, 0);
    }

    __syncthreads();
  }
#undef STAGE

  // ---- epilogue
  if (EPI == 1) {
    float bv[4];
#pragma unroll
    for (int n = 0; n < 4; ++n)
      bv[n] = bias[(size_t)e * N + bn * 128 + wc * 64 + n * 16 + fr];
    bf16* He = Hout + (size_t)e * MPE * N;

    // LDS-coalesced: 2 passes of 256 rows through As (64 KB contiguous).
    // Write: gelu'd bf16 at swizzled addr; Read: linear 16B -> 16B stores.
    bf16* Ls = &As[0][0];
#pragma unroll
    for (int P = 0; P < 2; ++P) {
      if ((wr >> 2) == P) {
        const int wrl = wr & 3;
#pragma unroll
        for (int m = 0; m < 4; ++m) {
#pragma unroll
          for (int j = 0; j < 4; ++j) {
            const int lr = wrl * 64 + m * 16 + fq * 4 + j;   // 0..255
#pragma unroll
            for (int n = 0; n < 4; ++n) {
              const int c = wc * 64 + n * 16 + fr;
              const int byteoff = lr * 256 + ((c * 2) ^ ((lr & 7) << 4));
              Ls[byteoff >> 1] = __float2bfloat16(fast_gelu(acc[m][n][j] + bv[n]));
            }
          }
        }
      }
      __syncthreads();
#pragma unroll
      for (int q = 0; q < 4; ++q) {
        const int o = (tid + q * 1024) * 16;       // byte offset in 64 KB
        const int lr = o >> 8;                     // 0..255
        const int cb = o & 255;                    // byte-in-row
        const int sb = lr * 256 + (cb ^ ((lr & 7) << 4));
        uint4 v = *(const uint4*)((const char*)Ls + sb);
        *(uint4*)&He[(size_t)(P * 256 + lr) * N + bn * 128 + (cb >> 1)] = v;
      }
      __syncthreads();
    }
  } else {
    float* Pd = Pout + (size_t)ks * T_NUM * H_DIM + (size_t)e * MPE * N;
#pragma unroll
    for (int m = 0; m < 4; ++m) {
#pragma unroll
      for (int j = 0; j < 4; ++j) {
        const int row = wr * 64 + m * 16 + fq * 4 + j;
#pragma unroll
        for (int n = 0; n < 4; ++n) {
          const int col = bn * 128 + wc * 64 + n * 16 + fr;
          Pd[(size_t)row * N + col] = acc[m][n][j];
        }
      }
    }
  }
}

// -------- reduce partials + bias + residual + LayerNorm + scatter ----------
__global__ __launch_bounds__(256)
void ln_resid2_kernel(float* __restrict__ out, const float* __restrict__ hs,
                      const float* __restrict__ p0, const float* __restrict__ p1,
                      const float* __restrict__ b2, const float* __restrict__ gamma,
                      const float* __restrict__ beta, const int* __restrict__ perm,
                      const int two) {
  const int r = blockIdx.x;
  const int t = threadIdx.x;
  const int e = r >> 9;
  const int drow = perm[r];
  float4 a = ((const float4*)(p0 + (size_t)r * H_DIM))[t];
  if (two) {
    float4 b = ((const float4*)(p1 + (size_t)r * H_DIM))[t];
    a.x += b.x; a.y += b.y; a.z += b.z; a.w += b.w;
  }
  float4 bb = ((const float4*)(b2 + (size_t)e * H_DIM))[t];
  float4 h  = ((const float4*)(hs + (size_t)drow * H_DIM))[t];
  float v0 = a.x + bb.x + h.x, v1 = a.y + bb.y + h.y;
  float v2 = a.z + bb.z + h.z, v3 = a.w + bb.w + h.w;
  float s  = v0 + v1 + v2 + v3;
  float sq = v0 * v0 + v1 * v1 + v2 * v2 + v3 * v3;
#pragma unroll
  for (int off = 32; off > 0; off >>= 1) {
    s  += __shfl_down(s, off);
    sq += __shfl_down(sq, off);
  }
  __shared__ float ss[4], ssq[4];
  const int wv = t >> 6;
  if ((t & 63) == 0) { ss[wv] = s; ssq[wv] = sq; }
  __syncthreads();
  s  = ss[0] + ss[1] + ss[2] + ss[3];
  sq = ssq[0] + ssq[1] + ssq[2] + ssq[3];
  const float mu  = s * (1.0f / (float)H_DIM);
  const float var = sq * (1.0f / (float)H_DIM) - mu * mu;
  const float rs  = rsqrtf(var + 1e-12f);
  float4 g = ((const float4*)gamma)[t];
  float4 b = ((const float4*)beta)[t];
  float4 rr;
  rr.x = (v0 - mu) * rs * g.x + b.x;
  rr.y = (v1 - mu) * rs * g.y + b.y;
  rr.z = (v2 - mu) * rs * g.z + b.z;
  rr.w = (v3 - mu) * rs * g.w + b.w;
  ((float4*)(out + (size_t)drow * H_DIM))[t] = rr;
}

extern "C" void kernel_launch(void* const* d_in, const int* in_sizes, int n_in,
                              void* d_out, int out_size, void* d_ws, size_t ws_size,
                              hipStream_t stream) {
  const float* hs    = (const float*)d_in[0];
  const int*   perm  = (const int*)d_in[1];
  const float* w1    = (const float*)d_in[2];
  const float* b1    = (const float*)d_in[3];
  const float* w2    = (const float*)d_in[4];
  const float* b2    = (const float*)d_in[5];
  const float* gamma = (const float*)d_in[6];
  const float* beta  = (const float*)d_in[7];
  float* out = (float*)d_out;

  const size_t xp_b   = (size_t)T_NUM * H_DIM * sizeof(bf16);   // 16 MB
  const size_t hbuf_b = (size_t)T_NUM * I_DIM * sizeof(bf16);   // 64 MB
  const size_t part_b = (size_t)T_NUM * H_DIM * sizeof(float);  // 32 MB each

  bf16*  xp   = (bf16*)d_ws;
  bf16*  hbuf = (bf16*)((char*)d_ws + xp_b);
  float* pbuf = (float*)((char*)d_ws + xp_b + hbuf_b);

  gather_cast_kernel<<<T_NUM, 256, 0, stream>>>(hs, perm, (uint32_t*)xp);

  // GEMM1: BM=512 (w1 fetched once). grid = 32 bn x 16 e = 512
  moe_gemm_kernel<1, 1, I_DIM, H_DIM, H_DIM, 5>
      <<<512, 1024, 0, stream>>>(xp, w1, b1, hbuf, nullptr);

  if (ws_size >= xp_b + hbuf_b + 2 * part_b) {
    // GEMM2 split-K=2 (R8-validated ~115 us): grid = 8 bn x 2 ks x 16 e = 256
    moe_gemm_kernel<0, 2, H_DIM, I_DIM, I_DIM / 2, 3>
        <<<256, 1024, 0, stream>>>(hbuf, w2, nullptr, nullptr, pbuf);
    ln_resid2_kernel<<<T_NUM, 256, 0, stream>>>(out, hs, pbuf, pbuf + (size_t)T_NUM * H_DIM,
                                                b2, gamma, beta, perm, 1);
  } else {
    moe_gemm_kernel<0, 1, H_DIM, I_DIM, I_DIM, 3>
        <<<128, 1024, 0, stream>>>(hbuf, w2, nullptr, nullptr, pbuf);
    ln_resid2_kernel<<<T_NUM, 256, 0, stream>>>(out, hs, pbuf, nullptr,
                                                b2, gamma, beta, perm, 0);
  }
}

// Round 16
// 316.686 us; speedup vs baseline: 1.3867x; 1.0221x over previous
//
#include <hip/hip_runtime.h>
#include <hip/hip_bf16.h>
#include <stdint.h>

#define E_NUM 16
#define T_NUM 8192
#define H_DIM 1024
#define I_DIM 4096
#define MPE   512   // tokens per expert

typedef __attribute__((ext_vector_type(8))) short short8;
typedef __attribute__((ext_vector_type(4))) float f32x4;
using bf16 = __hip_bfloat16;

typedef const __attribute__((address_space(1))) void GLV;
typedef __attribute__((address_space(3))) void LDSV;

__device__ __forceinline__ uint32_t pack2_bf16(float a, float b) {
  union { float f; uint32_t u; } ua, ub;
  ua.f = a; ub.f = b;
  uint32_t x = ua.u + (0x7FFFu + ((ua.u >> 16) & 1u));
  uint32_t y = ub.u + (0x7FFFu + ((ub.u >> 16) & 1u));
  return (x >> 16) | (y & 0xFFFF0000u);
}

// 8 f32 (two f32x4) -> short8 of bf16 (RNE, v_cvt_pk_bf16_f32)
__device__ __forceinline__ short8 cvt8(f32x4 a, f32x4 b) {
  union { short8 s; __hip_bfloat162 h[4]; } r;
  r.h[0] = __float22bfloat162_rn({a[0], a[1]});
  r.h[1] = __float22bfloat162_rn({a[2], a[3]});
  r.h[2] = __float22bfloat162_rn({b[0], b[1]});
  r.h[3] = __float22bfloat162_rn({b[2], b[3]});
  return r.s;
}

// fast GELU (validated R10/R12/R13/R15: absmax unchanged at 0.03125)
__device__ __forceinline__ float fast_gelu(float x) {
  const float p = x * fmaf(x * x, -0.0713548162726f, -1.59576912161f);
  return x * __builtin_amdgcn_rcpf(1.0f + __expf(p));
}

// ---------------- gather + cast: xp[r] = bf16(hs[perm[r]]) ----------------
__global__ __launch_bounds__(256)
void gather_cast_kernel(const float* __restrict__ hs, const int* __restrict__ perm,
                        uint32_t* __restrict__ xp) {
  const int r = blockIdx.x;
  const int t = threadIdx.x;
  const int src = perm[r];
  float4 v = ((const float4*)(hs + (size_t)src * H_DIM))[t];
  uint2 o;
  o.x = pack2_bf16(v.x, v.y);
  o.y = pack2_bf16(v.z, v.w);
  ((uint2*)(xp + (size_t)r * (H_DIM / 2)))[t] = o;
}

// ---------------- grouped GEMM, BM=512, TRIPLE-BUF counted pipeline ---------
// C = A(bf16,[E][512][KFULL]) * B(f32,[E][N][KFULL])^T over K window.
// BM=512, BN=128, BK=32, 1024 thr = 16 waves (8M x 2N), acc 4x4 f32x4.
// R15's kernel with ONE change: 3 LDS buffers (144 KB) + 2-tiles-ahead issue +
// counted s_waitcnt vmcnt(3) (never 0 in steady state) + raw s_barrier, so
// each tile's loads have ~2 full iterations to land (covers ~900 cyc latency).
// EPI=1: gelu -> bf16 Hout via LDS-coalesced epilogue (R15-validated).
// EPI=0: f32 partial to Pout (split-K).
template<int EPI, int KSPLIT, int N, int KFULL, int KLEN, int LOG_NBN>
__global__ __launch_bounds__(1024, 4)
void moe_gemm_kernel(const bf16* __restrict__ A, const float* __restrict__ Bw,
                     const float* __restrict__ bias, bf16* __restrict__ Hout,
                     float* __restrict__ Pout) {
  constexpr int NK = KLEN / 32;
  __shared__ bf16  As[3][512 * 32];   // 32 KB each (epilogue reuses As[0..1])
  __shared__ float Bs[3][128 * 32];   // 16 KB each   (total 144 KB)

  // bijective chunked XCD swizzle (m204); nwg % 8 == 0
  const int nwg = gridDim.x, qx = nwg >> 3, orig = blockIdx.x;
  const int wg = (orig & 7) * qx + (orig >> 3);
  const int bn   = wg & ((1 << LOG_NBN) - 1);
  const int rest = wg >> LOG_NBN;
  const int ks = (KSPLIT == 2) ? (rest & 1) : 0;
  const int e  = (KSPLIT == 2) ? (rest >> 1) : rest;
  const int K0 = ks * KLEN;

  const int tid = threadIdx.x;
  const int l = tid & 63;
  const int w = tid >> 6;                  // 0..15
  const int wr = w >> 1, wc = w & 1;       // 8 M-waves x 2 N-waves
  const int fr = l & 15, fq = l >> 4;
  const int rx = fr & 7;

  const bf16*  Ae = A  + (size_t)e * MPE * KFULL + K0;
  const float* Be = Bw + ((size_t)e * N + (size_t)bn * 128) * KFULL + K0;

  // A staging (R8/R15-validated): lds-row p = i*128 + (tid>>3), slot s = tid&7,
  // g = s^(p&7); real row = p + 256*(g>>2), k-chunk (g&3)*8.
  const int apq = tid >> 3;
  const int ag  = (tid & 7) ^ (apq & 7);
  const bf16* As0 = Ae + (size_t)(apq       + 256 * (ag >> 2)) * KFULL + (ag & 3) * 8;
  const bf16* As1 = Ae + (size_t)(apq + 128 + 256 * (ag >> 2)) * KFULL + (ag & 3) * 8;

  // B staging (R8/R15-validated): row = tid>>3, slot = tid&7, g = slot^(row&7)
  const float* Bsrc = Be + (size_t)(tid >> 3) * KFULL + ((tid & 7) ^ ((tid >> 3) & 7)) * 4;

  // fragment read offsets (R8/R15-validated)
  const int aso = (((((wr >> 2) << 2)) | fq) ^ rx) * 8;
  const int bp0 = (((fq << 1))     ^ rx) * 4;
  const int bp1 = (((fq << 1) | 1) ^ rx) * 4;

#define STAGE(buf, kt)                                                              \
  {                                                                                 \
    __builtin_amdgcn_global_load_lds((GLV*)(As0 + (kt) * 32),                       \
                                     (LDSV*)&As[buf][tid * 8], 16, 0, 0);           \
    __builtin_amdgcn_global_load_lds((GLV*)(As1 + (kt) * 32),                       \
                                     (LDSV*)&As[buf][(1024 + tid) * 8], 16, 0, 0);  \
    __builtin_amdgcn_global_load_lds((GLV*)(Bsrc + (kt) * 32),                      \
                                     (LDSV*)&Bs[buf][tid * 4], 16, 0, 0);           \
  }

  f32x4 acc[4][4];
#pragma unroll
  for (int m = 0; m < 4; ++m)
#pragma unroll
    for (int n = 0; n < 4; ++n) acc[m][n] = (f32x4){0.f, 0.f, 0.f, 0.f};

  // ---- prologue: S(0), S(1) issued; S(0) landed; S(1) stays in flight
  STAGE(0, 0);
  STAGE(1, 1);
  asm volatile("s_waitcnt vmcnt(3)" ::: "memory");
  __builtin_amdgcn_sched_barrier(0);
  __builtin_amdgcn_s_barrier();
  __builtin_amdgcn_sched_barrier(0);

  int bufc = 0, bufn1 = 1, bufn2 = 2;
  for (int t = 0; t < NK; ++t) {
    // issue S(t+2) into the buffer whose readers finished last iteration
    if (t + 2 < NK) STAGE(bufn2, t + 2);

    short8 a8[4];
#pragma unroll
    for (int m = 0; m < 4; ++m)
      a8[m] = *(const short8*)&As[bufc][((wr & 3) * 64 + m * 16 + fr) * 64 + aso];

#pragma unroll
    for (int n = 0; n < 4; ++n) {
      const int col = wc * 64 + n * 16 + fr;
      const f32x4 x0 = *(const f32x4*)&Bs[bufc][col * 32 + bp0];
      const f32x4 x1 = *(const f32x4*)&Bs[bufc][col * 32 + bp1];
      const short8 b8 = cvt8(x0, x1);
#pragma unroll
      for (int m = 0; m < 4; ++m)
        acc[m][n] = __builtin_amdgcn_mfma_f32_16x16x32_bf16(a8[m], b8, acc[m][n], 0, 0, 0);
    }

    // counted drain: S(t+1) must be landed for next iter; S(t+2) stays flying
    if (t + 2 < NK) {
      asm volatile("s_waitcnt vmcnt(3)" ::: "memory");
      __builtin_amdgcn_sched_barrier(0);
      __builtin_amdgcn_s_barrier();
      __builtin_amdgcn_sched_barrier(0);
    } else if (t + 1 < NK) {
      asm volatile("s_waitcnt vmcnt(0)" ::: "memory");
      __builtin_amdgcn_sched_barrier(0);
      __builtin_amdgcn_s_barrier();
      __builtin_amdgcn_sched_barrier(0);
    }

    const int b0 = bufc;
    bufc = bufn1; bufn1 = bufn2; bufn2 = b0;
  }
#undef STAGE
  __syncthreads();   // all waves done computing before epilogue LDS reuse

  // ---- epilogue
  if (EPI == 1) {
    float bv[4];
#pragma unroll
    for (int n = 0; n < 4; ++n)
      bv[n] = bias[(size_t)e * N + bn * 128 + wc * 64 + n * 16 + fr];
    bf16* He = Hout + (size_t)e * MPE * N;

    // LDS-coalesced (R15-validated): 2 passes of 256 rows through As[0..1].
    bf16* Ls = &As[0][0];
#pragma unroll
    for (int P = 0; P < 2; ++P) {
      if ((wr >> 2) == P) {
        const int wrl = wr & 3;
#pragma unroll
        for (int m = 0; m < 4; ++m) {
#pragma unroll
          for (int j = 0; j < 4; ++j) {
            const int lr = wrl * 64 + m * 16 + fq * 4 + j;   // 0..255
#pragma unroll
            for (int n = 0; n < 4; ++n) {
              const int c = wc * 64 + n * 16 + fr;
              const int byteoff = lr * 256 + ((c * 2) ^ ((lr & 7) << 4));
              Ls[byteoff >> 1] = __float2bfloat16(fast_gelu(acc[m][n][j] + bv[n]));
            }
          }
        }
      }
      __syncthreads();
#pragma unroll
      for (int q = 0; q < 4; ++q) {
        const int o = (tid + q * 1024) * 16;       // byte offset in 64 KB
        const int lr = o >> 8;                     // 0..255
        const int cb = o & 255;                    // byte-in-row
        const int sb = lr * 256 + (cb ^ ((lr & 7) << 4));
        uint4 v = *(const uint4*)((const char*)Ls + sb);
        *(uint4*)&He[(size_t)(P * 256 + lr) * N + bn * 128 + (cb >> 1)] = v;
      }
      __syncthreads();
    }
  } else {
    float* Pd = Pout + (size_t)ks * T_NUM * H_DIM + (size_t)e * MPE * N;
#pragma unroll
    for (int m = 0; m < 4; ++m) {
#pragma unroll
      for (int j = 0; j < 4; ++j) {
        const int row = wr * 64 + m * 16 + fq * 4 + j;
#pragma unroll
        for (int n = 0; n < 4; ++n) {
          const int col = bn * 128 + wc * 64 + n * 16 + fr;
          Pd[(size_t)row * N + col] = acc[m][n][j];
        }
      }
    }
  }
}

// -------- reduce partials + bias + residual + LayerNorm + scatter ----------
__global__ __launch_bounds__(256)
void ln_resid2_kernel(float* __restrict__ out, const float* __restrict__ hs,
                      const float* __restrict__ p0, const float* __restrict__ p1,
                      const float* __restrict__ b2, const float* __restrict__ gamma,
                      const float* __restrict__ beta, const int* __restrict__ perm,
                      const int two) {
  const int r = blockIdx.x;
  const int t = threadIdx.x;
  const int e = r >> 9;
  const int drow = perm[r];
  float4 a = ((const float4*)(p0 + (size_t)r * H_DIM))[t];
  if (two) {
    float4 b = ((const float4*)(p1 + (size_t)r * H_DIM))[t];
    a.x += b.x; a.y += b.y; a.z += b.z; a.w += b.w;
  }
  float4 bb = ((const float4*)(b2 + (size_t)e * H_DIM))[t];
  float4 h  = ((const float4*)(hs + (size_t)drow * H_DIM))[t];
  float v0 = a.x + bb.x + h.x, v1 = a.y + bb.y + h.y;
  float v2 = a.z + bb.z + h.z, v3 = a.w + bb.w + h.w;
  float s  = v0 + v1 + v2 + v3;
  float sq = v0 * v0 + v1 * v1 + v2 * v2 + v3 * v3;
#pragma unroll
  for (int off = 32; off > 0; off >>= 1) {
    s  += __shfl_down(s, off);
    sq += __shfl_down(sq, off);
  }
  __shared__ float ss[4], ssq[4];
  const int wv = t >> 6;
  if ((t & 63) == 0) { ss[wv] = s; ssq[wv] = sq; }
  __syncthreads();
  s  = ss[0] + ss[1] + ss[2] + ss[3];
  sq = ssq[0] + ssq[1] + ssq[2] + ssq[3];
  const float mu  = s * (1.0f / (float)H_DIM);
  const float var = sq * (1.0f / (float)H_DIM) - mu * mu;
  const float rs  = rsqrtf(var + 1e-12f);
  float4 g = ((const float4*)gamma)[t];
  float4 b = ((const float4*)beta)[t];
  float4 rr;
  rr.x = (v0 - mu) * rs * g.x + b.x;
  rr.y = (v1 - mu) * rs * g.y + b.y;
  rr.z = (v2 - mu) * rs * g.z + b.z;
  rr.w = (v3 - mu) * rs * g.w + b.w;
  ((float4*)(out + (size_t)drow * H_DIM))[t] = rr;
}

extern "C" void kernel_launch(void* const* d_in, const int* in_sizes, int n_in,
                              void* d_out, int out_size, void* d_ws, size_t ws_size,
                              hipStream_t stream) {
  const float* hs    = (const float*)d_in[0];
  const int*   perm  = (const int*)d_in[1];
  const float* w1    = (const float*)d_in[2];
  const float* b1    = (const float*)d_in[3];
  const float* w2    = (const float*)d_in[4];
  const float* b2    = (const float*)d_in[5];
  const float* gamma = (const float*)d_in[6];
  const float* beta  = (const float*)d_in[7];
  float* out = (float*)d_out;

  const size_t xp_b   = (size_t)T_NUM * H_DIM * sizeof(bf16);   // 16 MB
  const size_t hbuf_b = (size_t)T_NUM * I_DIM * sizeof(bf16);   // 64 MB
  const size_t part_b = (size_t)T_NUM * H_DIM * sizeof(float);  // 32 MB each

  bf16*  xp   = (bf16*)d_ws;
  bf16*  hbuf = (bf16*)((char*)d_ws + xp_b);
  float* pbuf = (float*)((char*)d_ws + xp_b + hbuf_b);

  gather_cast_kernel<<<T_NUM, 256, 0, stream>>>(hs, perm, (uint32_t*)xp);

  // GEMM1: BM=512 (w1 fetched once). grid = 32 bn x 16 e = 512
  moe_gemm_kernel<1, 1, I_DIM, H_DIM, H_DIM, 5>
      <<<512, 1024, 0, stream>>>(xp, w1, b1, hbuf, nullptr);

  if (ws_size >= xp_b + hbuf_b + 2 * part_b) {
    // GEMM2 split-K=2: grid = 8 bn x 2 ks x 16 e = 256
    moe_gemm_kernel<0, 2, H_DIM, I_DIM, I_DIM / 2, 3>
        <<<256, 1024, 0, stream>>>(hbuf, w2, nullptr, nullptr, pbuf);
    ln_resid2_kernel<<<T_NUM, 256, 0, stream>>>(out, hs, pbuf, pbuf + (size_t)T_NUM * H_DIM,
                                                b2, gamma, beta, perm, 1);
  } else {
    moe_gemm_kernel<0, 1, H_DIM, I_DIM, I_DIM, 3>
        <<<128, 1024, 0, stream>>>(hbuf, w2, nullptr, nullptr, pbuf);
    ln_resid2_kernel<<<T_NUM, 256, 0, stream>>>(out, hs, pbuf, nullptr,
                                                b2, gamma, beta, perm, 0);
  }
}